// Round 1
// baseline (629.729 us; speedup 1.0000x reference)
//
#include <hip/hip_runtime.h>
#include <math.h>

#define IN_DIM 512
#define NH 4
#define OD 64
#define HD 256   // NH*OD

typedef float  floatx4 __attribute__((ext_vector_type(4)));
typedef short  shortx8 __attribute__((ext_vector_type(8)));

__device__ __forceinline__ unsigned short f2bf(float x) {
    unsigned int u = __float_as_uint(x);
    u += 0x7fffu + ((u >> 16) & 1u);          // round-to-nearest-even
    return (unsigned short)(u >> 16);
}
__device__ __forceinline__ float bf2f(unsigned short u) {
    return __uint_as_float(((unsigned int)u) << 16);
}

// ---------------------------------------------------------------- prep
// zero deg[M] + sumexp[4M]; W fp32 [512][256] -> Wt bf16 [256][512]
__global__ void prep_kernel(const float* __restrict__ W, ushort* __restrict__ Wt,
                            int* __restrict__ deg, float* __restrict__ sumexp,
                            int M) {
    int t = blockIdx.x * blockDim.x + threadIdx.x;
    if (t < M) deg[t] = 0;
    if (t < 4 * M) sumexp[t] = 0.f;
    if (t < 256 * 64) {
        int n = t >> 6;
        int k8 = (t & 63) * 8;
        shortx8 v;
        #pragma unroll
        for (int j = 0; j < 8; ++j) v[j] = (short)f2bf(W[(size_t)(k8 + j) * HD + n]);
        *(shortx8*)&Wt[(size_t)n * IN_DIM + k8] = v;
    }
}

// ---------------------------------------------------------------- MFMA GEMM (+scores)
// h_bf16 = bf16(x) @ W : tile 64(M) x 256(N), BK=64, 4 waves (each 64m x 64n).
// Wave w's columns == head w, so s_src/s_dst are computed in-epilogue from the
// fp32 accumulators via a 16-lane shfl reduction.
__global__ __launch_bounds__(256) void gemm_kernel(const float* __restrict__ x,
                                                   const ushort* __restrict__ Wt,
                                                   ushort* __restrict__ h,
                                                   const float* __restrict__ a,
                                                   float* __restrict__ s_src,
                                                   float* __restrict__ s_dst,
                                                   int M) {
    __shared__ ushort As[64 * 64];     // [row m][64 k]  8 KB
    __shared__ ushort Bs[256 * 64];    // [row n][64 k] 32 KB
    const int tid = threadIdx.x;
    const int lane = tid & 63;
    const int w = tid >> 6;
    const int bm = blockIdx.x * 64;
    const int wn = w * 64;
    const int lm = lane & 15;          // fragment row
    const int lq = lane >> 4;          // quad
    floatx4 acc[4][4];
    #pragma unroll
    for (int i = 0; i < 4; ++i)
        #pragma unroll
        for (int j = 0; j < 4; ++j) acc[i][j] = (floatx4){0.f, 0.f, 0.f, 0.f};

    for (int k0 = 0; k0 < IN_DIM; k0 += 64) {
        #pragma unroll
        for (int j = 0; j < 2; ++j) {
            int ch = tid * 2 + j;
            int row = ch >> 3;
            int c = (ch & 7) ^ (row & 7);        // XOR swizzle (2-way b128: free, m136)
            int gr = bm + row;
            shortx8 v = (shortx8){0, 0, 0, 0, 0, 0, 0, 0};
            if (gr < M) {
                const float* gp = &x[(size_t)gr * IN_DIM + k0 + c * 8];
                float4 v0 = *(const float4*)gp;
                float4 v1 = *(const float4*)(gp + 4);
                v[0] = (short)f2bf(v0.x); v[1] = (short)f2bf(v0.y);
                v[2] = (short)f2bf(v0.z); v[3] = (short)f2bf(v0.w);
                v[4] = (short)f2bf(v1.x); v[5] = (short)f2bf(v1.y);
                v[6] = (short)f2bf(v1.z); v[7] = (short)f2bf(v1.w);
            }
            *(shortx8*)&As[ch * 8] = v;
        }
        #pragma unroll
        for (int j = 0; j < 8; ++j) {
            int ch = j * 256 + tid;
            int row = ch >> 3;
            int c = (ch & 7) ^ (row & 7);
            const ushort* gp = &Wt[(size_t)row * IN_DIM + k0 + c * 8];
            __builtin_amdgcn_global_load_lds(
                (const __attribute__((address_space(1))) void*)gp,
                (__attribute__((address_space(3))) void*)&Bs[(size_t)(j * 256 + wn) * 8],
                16, 0, 0);
        }
        __syncthreads();
        #pragma unroll
        for (int kk = 0; kk < 2; ++kk) {
            shortx8 af[4], bfr[4];
            #pragma unroll
            for (int mt = 0; mt < 4; ++mt) {
                int row = mt * 16 + lm;
                int c = (kk * 4 + lq) ^ (row & 7);
                af[mt] = *(const shortx8*)&As[row * 64 + c * 8];
            }
            #pragma unroll
            for (int nt = 0; nt < 4; ++nt) {
                int row = wn + nt * 16 + lm;
                int c = (kk * 4 + lq) ^ (row & 7);
                bfr[nt] = *(const shortx8*)&Bs[row * 64 + c * 8];
            }
            #pragma unroll
            for (int mt = 0; mt < 4; ++mt)
                #pragma unroll
                for (int nt = 0; nt < 4; ++nt)
                    acc[mt][nt] = __builtin_amdgcn_mfma_f32_16x16x32_bf16(
                        af[mt], bfr[nt], acc[mt][nt], 0, 0, 0);
        }
        __syncthreads();
    }
    // ---- fused scores: s_src[m,w], s_dst[m,w] from fp32 acc
    float as_l[4], ad_l[4];
    #pragma unroll
    for (int nt = 0; nt < 4; ++nt) {
        as_l[nt] = a[w * 2 * OD + nt * 16 + lm];
        ad_l[nt] = a[w * 2 * OD + OD + nt * 16 + lm];
    }
    #pragma unroll
    for (int mt = 0; mt < 4; ++mt)
        #pragma unroll
        for (int r = 0; r < 4; ++r) {
            float ps = 0.f, pd = 0.f;
            #pragma unroll
            for (int nt = 0; nt < 4; ++nt) {
                float v = acc[mt][nt][r];
                ps += v * as_l[nt];
                pd += v * ad_l[nt];
            }
            #pragma unroll
            for (int off = 1; off < 16; off <<= 1) {
                ps += __shfl_xor(ps, off, 64);
                pd += __shfl_xor(pd, off, 64);
            }
            int m = bm + mt * 16 + lq * 4 + r;
            if (m < M && lm == 0) {
                s_src[m * NH + w] = ps;
                s_dst[m * NH + w] = pd;
            }
        }
    // ---- h store: C/D layout col=lane&15, row=(lane>>4)*4+reg  [m89/m91]
    #pragma unroll
    for (int mt = 0; mt < 4; ++mt)
        #pragma unroll
        for (int r = 0; r < 4; ++r) {
            int m = bm + mt * 16 + lq * 4 + r;
            if (m < M) {
                #pragma unroll
                for (int nt = 0; nt < 4; ++nt)
                    h[(size_t)m * HD + wn + nt * 16 + lm] = f2bf(acc[mt][nt][r]);
            }
        }
}

// ---------------------------------------------------------------- pass 1: deg count + src softmax denominator
// edge-parallel: atomicAdd deg[dst]; atomicAdd exp(lrelu(s_src+s_dst)) into
// sumexp[src*4+h]. 3.2M float atomics, avg 16 per address -> cheap.
// |e|<=~6: fp32-safe without max-subtraction (verified in earlier rounds).
__global__ void count_sum_kernel(const int2* __restrict__ edges,
                                 const float* __restrict__ s_src,
                                 const float* __restrict__ s_dst,
                                 int* __restrict__ deg,
                                 float* __restrict__ sumexp, int E) {
    int i = blockIdx.x * blockDim.x + threadIdx.x;
    if (i >= E) return;
    int2 e = edges[i];
    atomicAdd(&deg[e.y], 1);
    float4 ss = *(const float4*)&s_src[(size_t)e.x * NH];
    float4 sd = *(const float4*)&s_dst[(size_t)e.y * NH];
    float a0 = ss.x + sd.x, a1 = ss.y + sd.y, a2 = ss.z + sd.z, a3 = ss.w + sd.w;
    a0 = a0 > 0.f ? a0 : 0.2f * a0;
    a1 = a1 > 0.f ? a1 : 0.2f * a1;
    a2 = a2 > 0.f ? a2 : 0.2f * a2;
    a3 = a3 > 0.f ? a3 : 0.2f * a3;
    atomicAdd(&sumexp[(size_t)e.x * NH + 0], __expf(a0));
    atomicAdd(&sumexp[(size_t)e.x * NH + 1], __expf(a1));
    atomicAdd(&sumexp[(size_t)e.x * NH + 2], __expf(a2));
    atomicAdd(&sumexp[(size_t)e.x * NH + 3], __expf(a3));
}

// ---------------------------------------------------------------- scan
// single-block exclusive scan of deg[M] -> ptr[M+1]; cursor = copy of ptr.
__global__ __launch_bounds__(1024) void scan_kernel(const int* __restrict__ deg,
                                                    int* __restrict__ ptr,
                                                    int* __restrict__ cursor, int M) {
    __shared__ int sdata[1024];
    const int t = threadIdx.x;
    const int C = (M + 1023) >> 10;
    const int base = t * C;
    int sum = 0;
    for (int j = 0; j < C; ++j) {
        int i = base + j;
        if (i < M) sum += deg[i];
    }
    sdata[t] = sum;
    __syncthreads();
    for (int off = 1; off < 1024; off <<= 1) {
        int v = (t >= off) ? sdata[t - off] : 0;
        __syncthreads();
        sdata[t] += v;
        __syncthreads();
    }
    int run = sdata[t] - sum;          // exclusive base for this thread's segment
    for (int j = 0; j < C; ++j) {
        int i = base + j;
        if (i < M) {
            ptr[i] = run;
            cursor[i] = run;
            run += deg[i];
        }
    }
    if (t == 1023) ptr[M] = run;
}

// ---------------------------------------------------------------- pass 2: scatter srcs into CSR buckets
__global__ void scatter_kernel(const int2* __restrict__ edges,
                               int* __restrict__ cursor,
                               int* __restrict__ csr_src, int E) {
    int i = blockIdx.x * blockDim.x + threadIdx.x;
    if (i >= E) return;
    int2 e = edges[i];
    int pos = atomicAdd(&cursor[e.y], 1);
    csr_src[pos] = e.x;
}

// ---------------------------------------------------------------- gather (CSR)
// one wave per dst node; the two 32-lane halves take alternating edges of the
// node's contiguous CSR list, unrolled 2x -> 4 fully independent edge streams
// per wave (no pointer chase). Lane covers 8 channels (shortx8 = 16B h-load).
// alpha recomputed in-register: s_src/sumexp loads are 8-lane broadcasts.
__global__ __launch_bounds__(256) void gather_kernel(
        const int* __restrict__ ptr, const int* __restrict__ csr_src,
        const float* __restrict__ s_src, const float* __restrict__ sumexp,
        const float* __restrict__ s_dst, const ushort* __restrict__ h,
        const float* __restrict__ bias, float* __restrict__ out, int M) {
    int lane = threadIdx.x & 63;
    int n = blockIdx.x * 4 + (threadIdx.x >> 6);
    if (n >= M) return;
    int half = lane >> 5;
    int l5 = lane & 31;
    int head = l5 >> 3;            // 8 lanes per head
    int c0 = l5 * 8;               // channel base 0..248
    float sdst = s_dst[n * NH + head];
    floatx4 accA = {0.f, 0.f, 0.f, 0.f}, accB = {0.f, 0.f, 0.f, 0.f};
    int beg = ptr[n], end = ptr[n + 1];
    int e = beg + half;

#define GAT_EDGE(SS, SM, HU) do {                                              \
        float es_ = (SS) + sdst;                                               \
        es_ = es_ > 0.f ? es_ : 0.2f * es_;                                    \
        float al_ = __expf(es_) * __builtin_amdgcn_rcpf((SM) + 1e-10f);        \
        accA.x += al_ * bf2f((ushort)(HU)[0]);                                 \
        accA.y += al_ * bf2f((ushort)(HU)[1]);                                 \
        accA.z += al_ * bf2f((ushort)(HU)[2]);                                 \
        accA.w += al_ * bf2f((ushort)(HU)[3]);                                 \
        accB.x += al_ * bf2f((ushort)(HU)[4]);                                 \
        accB.y += al_ * bf2f((ushort)(HU)[5]);                                 \
        accB.z += al_ * bf2f((ushort)(HU)[6]);                                 \
        accB.w += al_ * bf2f((ushort)(HU)[7]);                                 \
    } while (0)

    for (; e + 2 < end; e += 4) {
        int s0 = csr_src[e];
        int s1 = csr_src[e + 2];
        float ss0 = s_src[(size_t)s0 * NH + head];
        float sm0 = sumexp[(size_t)s0 * NH + head];
        float ss1 = s_src[(size_t)s1 * NH + head];
        float sm1 = sumexp[(size_t)s1 * NH + head];
        shortx8 h0 = *(const shortx8*)&h[(size_t)s0 * HD + c0];
        shortx8 h1 = *(const shortx8*)&h[(size_t)s1 * HD + c0];
        GAT_EDGE(ss0, sm0, h0);
        GAT_EDGE(ss1, sm1, h1);
    }
    if (e < end) {
        int s0 = csr_src[e];
        float ss0 = s_src[(size_t)s0 * NH + head];
        float sm0 = sumexp[(size_t)s0 * NH + head];
        shortx8 h0 = *(const shortx8*)&h[(size_t)s0 * HD + c0];
        GAT_EDGE(ss0, sm0, h0);
    }
#undef GAT_EDGE

    // combine the two halves (same channels, different edges)
    accA.x += __shfl_xor(accA.x, 32, 64); accA.y += __shfl_xor(accA.y, 32, 64);
    accA.z += __shfl_xor(accA.z, 32, 64); accA.w += __shfl_xor(accA.w, 32, 64);
    accB.x += __shfl_xor(accB.x, 32, 64); accB.y += __shfl_xor(accB.y, 32, 64);
    accB.z += __shfl_xor(accB.z, 32, 64); accB.w += __shfl_xor(accB.w, 32, 64);
    if (half == 0) {
        float4 b0 = *(const float4*)&bias[c0];
        float4 b1 = *(const float4*)&bias[c0 + 4];
        float4 o0 = make_float4(accA.x + b0.x, accA.y + b0.y, accA.z + b0.z, accA.w + b0.w);
        float4 o1 = make_float4(accB.x + b1.x, accB.y + b1.y, accB.z + b1.z, accB.w + b1.w);
        *(float4*)&out[(size_t)n * HD + c0] = o0;
        *(float4*)&out[(size_t)n * HD + c0 + 4] = o1;
    }
}

// ---------------------------------------------------------------- launch
extern "C" void kernel_launch(void* const* d_in, const int* in_sizes, int n_in,
                              void* d_out, int out_size, void* d_ws, size_t ws_size,
                              hipStream_t stream) {
    const float* x     = (const float*)d_in[0];
    const int2*  edges = (const int2*)d_in[1];
    const float* W     = (const float*)d_in[2];
    const float* a     = (const float*)d_in[3];
    const float* bias  = (const float*)d_in[4];
    float* out = (float*)d_out;
    const int M = in_sizes[0] / IN_DIM;   // 50000
    const int E = in_sizes[1] / 2;        // 800000

    char* p = (char*)d_ws;
    ushort* hB      = (ushort*)p; p += (size_t)M * HD * sizeof(ushort);      // 25.6 MB
    ushort* Wt      = (ushort*)p; p += (size_t)HD * IN_DIM * sizeof(ushort); // 256 KB
    float*  s_src   = (float*)p;  p += (size_t)M * NH * sizeof(float);       // 800 KB
    float*  s_dst   = (float*)p;  p += (size_t)M * NH * sizeof(float);       // 800 KB
    float*  sumexp  = (float*)p;  p += (size_t)M * NH * sizeof(float);       // 800 KB
    int*    deg     = (int*)p;    p += (size_t)M * sizeof(int);              // 200 KB
    int*    ptr     = (int*)p;    p += ((size_t)M + 4) * sizeof(int);        // 200 KB (16B-pad)
    int*    cursor  = (int*)p;    p += (size_t)M * sizeof(int);              // 200 KB
    int*    csr_src = (int*)p;    p += (size_t)E * sizeof(int);              // 3.2 MB

    prep_kernel<<<(4 * M + 255) / 256, 256, 0, stream>>>(W, Wt, deg, sumexp, M);
    gemm_kernel<<<(M + 63) / 64, 256, 0, stream>>>(x, Wt, hB, a, s_src, s_dst, M);
    count_sum_kernel<<<(E + 255) / 256, 256, 0, stream>>>(edges, s_src, s_dst,
                                                          deg, sumexp, E);
    scan_kernel<<<1, 1024, 0, stream>>>(deg, ptr, cursor, M);
    scatter_kernel<<<(E + 255) / 256, 256, 0, stream>>>(edges, cursor, csr_src, E);
    gather_kernel<<<(M + 3) / 4, 256, 0, stream>>>(ptr, csr_src, s_src, sumexp,
                                                   s_dst, hB, bias, out, M);
}

// Round 2
// 361.921 us; speedup vs baseline: 1.7400x; 1.7400x over previous
//
#include <hip/hip_runtime.h>
#include <math.h>

#define IN_DIM 512
#define NH 4
#define OD 64
#define HD 256   // NH*OD

typedef float  floatx4 __attribute__((ext_vector_type(4)));
typedef short  shortx8 __attribute__((ext_vector_type(8)));

__device__ __forceinline__ unsigned short f2bf(float x) {
    unsigned int u = __float_as_uint(x);
    u += 0x7fffu + ((u >> 16) & 1u);          // round-to-nearest-even
    return (unsigned short)(u >> 16);
}
__device__ __forceinline__ float bf2f(unsigned short u) {
    return __uint_as_float(((unsigned int)u) << 16);
}

// ---------------------------------------------------------------- prep
// head_src (16M) / head_dst (8M) = -1; W fp32 [512][256] -> Wt bf16 [256][512]
__global__ void prep_kernel(const float* __restrict__ W, ushort* __restrict__ Wt,
                            int* __restrict__ head_src, int* __restrict__ head_dst,
                            int M) {
    int t = blockIdx.x * blockDim.x + threadIdx.x;
    if (t < 16 * M) head_src[t] = -1;
    if (t < 8 * M) head_dst[t] = -1;
    if (t < 256 * 64) {
        int n = t >> 6;
        int k8 = (t & 63) * 8;
        shortx8 v;
        #pragma unroll
        for (int j = 0; j < 8; ++j) v[j] = (short)f2bf(W[(size_t)(k8 + j) * HD + n]);
        *(shortx8*)&Wt[(size_t)n * IN_DIM + k8] = v;
    }
}

// ---------------------------------------------------------------- MFMA GEMM (+scores)
// h_bf16 = bf16(x) @ W : tile 64(M) x 256(N), BK=64, 4 waves (each 64m x 64n).
// Wave w's columns == head w, so s_src/s_dst are computed in-epilogue from the
// fp32 accumulators via a 16-lane shfl reduction.
__global__ __launch_bounds__(256) void gemm_kernel(const float* __restrict__ x,
                                                   const ushort* __restrict__ Wt,
                                                   ushort* __restrict__ h,
                                                   const float* __restrict__ a,
                                                   float2* __restrict__ ssi,
                                                   float* __restrict__ s_dst,
                                                   int M) {
    __shared__ ushort As[64 * 64];     // [row m][64 k]  8 KB
    __shared__ ushort Bs[256 * 64];    // [row n][64 k] 32 KB
    const int tid = threadIdx.x;
    const int lane = tid & 63;
    const int w = tid >> 6;
    const int bm = blockIdx.x * 64;
    const int wn = w * 64;
    const int lm = lane & 15;          // fragment row
    const int lq = lane >> 4;          // quad
    floatx4 acc[4][4];
    #pragma unroll
    for (int i = 0; i < 4; ++i)
        #pragma unroll
        for (int j = 0; j < 4; ++j) acc[i][j] = (floatx4){0.f, 0.f, 0.f, 0.f};

    for (int k0 = 0; k0 < IN_DIM; k0 += 64) {
        #pragma unroll
        for (int j = 0; j < 2; ++j) {
            int ch = tid * 2 + j;
            int row = ch >> 3;
            int c = (ch & 7) ^ (row & 7);        // XOR swizzle (2-way b128: free, m136)
            int gr = bm + row;
            shortx8 v = (shortx8){0, 0, 0, 0, 0, 0, 0, 0};
            if (gr < M) {
                const float* gp = &x[(size_t)gr * IN_DIM + k0 + c * 8];
                float4 v0 = *(const float4*)gp;
                float4 v1 = *(const float4*)(gp + 4);
                v[0] = (short)f2bf(v0.x); v[1] = (short)f2bf(v0.y);
                v[2] = (short)f2bf(v0.z); v[3] = (short)f2bf(v0.w);
                v[4] = (short)f2bf(v1.x); v[5] = (short)f2bf(v1.y);
                v[6] = (short)f2bf(v1.z); v[7] = (short)f2bf(v1.w);
            }
            *(shortx8*)&As[ch * 8] = v;
        }
        #pragma unroll
        for (int j = 0; j < 8; ++j) {
            int ch = j * 256 + tid;
            int row = ch >> 3;
            int c = (ch & 7) ^ (row & 7);
            const ushort* gp = &Wt[(size_t)row * IN_DIM + k0 + c * 8];
            __builtin_amdgcn_global_load_lds(
                (const __attribute__((address_space(1))) void*)gp,
                (__attribute__((address_space(3))) void*)&Bs[(size_t)(j * 256 + wn) * 8],
                16, 0, 0);
        }
        __syncthreads();
        #pragma unroll
        for (int kk = 0; kk < 2; ++kk) {
            shortx8 af[4], bfr[4];
            #pragma unroll
            for (int mt = 0; mt < 4; ++mt) {
                int row = mt * 16 + lm;
                int c = (kk * 4 + lq) ^ (row & 7);
                af[mt] = *(const shortx8*)&As[row * 64 + c * 8];
            }
            #pragma unroll
            for (int nt = 0; nt < 4; ++nt) {
                int row = wn + nt * 16 + lm;
                int c = (kk * 4 + lq) ^ (row & 7);
                bfr[nt] = *(const shortx8*)&Bs[row * 64 + c * 8];
            }
            #pragma unroll
            for (int mt = 0; mt < 4; ++mt)
                #pragma unroll
                for (int nt = 0; nt < 4; ++nt)
                    acc[mt][nt] = __builtin_amdgcn_mfma_f32_16x16x32_bf16(
                        af[mt], bfr[nt], acc[mt][nt], 0, 0, 0);
        }
        __syncthreads();
    }
    // ---- fused scores: s_src[m,w], s_dst[m,w] from fp32 acc
    float as_l[4], ad_l[4];
    #pragma unroll
    for (int nt = 0; nt < 4; ++nt) {
        as_l[nt] = a[w * 2 * OD + nt * 16 + lm];
        ad_l[nt] = a[w * 2 * OD + OD + nt * 16 + lm];
    }
    #pragma unroll
    for (int mt = 0; mt < 4; ++mt)
        #pragma unroll
        for (int r = 0; r < 4; ++r) {
            float ps = 0.f, pd = 0.f;
            #pragma unroll
            for (int nt = 0; nt < 4; ++nt) {
                float v = acc[mt][nt][r];
                ps += v * as_l[nt];
                pd += v * ad_l[nt];
            }
            #pragma unroll
            for (int off = 1; off < 16; off <<= 1) {
                ps += __shfl_xor(ps, off, 64);
                pd += __shfl_xor(pd, off, 64);
            }
            int m = bm + mt * 16 + lq * 4 + r;
            if (m < M && lm == 0) {
                ssi[m * NH + w].x = ps;
                s_dst[m * NH + w] = pd;
            }
        }
    // ---- h store: C/D layout col=lane&15, row=(lane>>4)*4+reg  [m89/m91]
    #pragma unroll
    for (int mt = 0; mt < 4; ++mt)
        #pragma unroll
        for (int r = 0; r < 4; ++r) {
            int m = bm + mt * 16 + lq * 4 + r;
            if (m < M) {
                #pragma unroll
                for (int nt = 0; nt < 4; ++nt)
                    h[(size_t)m * HD + wn + nt * 16 + lm] = f2bf(acc[mt][nt][r]);
            }
        }
}

// ---------------------------------------------------------------- link
// lock-free list push: 16 chains per src, 8 chains per dst (MLP for the walks).
// payload packed into next: next_src={next,dst}, next_dst={next,src}.
__global__ void link_kernel(const int2* __restrict__ edges,
                            int* __restrict__ head_src, int2* __restrict__ next_src,
                            int* __restrict__ head_dst, int2* __restrict__ next_dst,
                            int E) {
    int i = blockIdx.x * blockDim.x + threadIdx.x;
    if (i >= E) return;
    int2 e = edges[i];
    int ps = atomicExch(&head_src[16 * e.x + (i & 15)], i);
    next_src[i] = make_int2(ps, e.y);
    int pd = atomicExch(&head_dst[8 * e.y + (i & 7)], i);
    next_dst[i] = make_int2(pd, e.x);
}

// ---------------------------------------------------------------- src sums
// ONE WAVE per src node (was 1 thread -> 781 waves total, occupancy-starved).
// lane = slot*4 + head: 16 slots each own a chain; the 4 lanes of a slot walk
// it in lockstep (broadcast loads), each handling one head. shfl_xor reduce
// over slots; lanes 0..3 write inv_sum. Avg chain length = 1. NO atomics.
__global__ __launch_bounds__(256) void src_sum_kernel(const int* __restrict__ head_src,
                                                      const int2* __restrict__ next_src,
                                                      float2* __restrict__ ssi,
                                                      const float* __restrict__ s_dst, int M) {
    int lane = threadIdx.x & 63;
    int n = blockIdx.x * 4 + (threadIdx.x >> 6);
    if (n >= M) return;
    int slot = lane >> 2;
    int hd = lane & 3;
    float ss = ssi[n * NH + hd].x;
    float sum = 0.f;
    int e = head_src[16 * n + slot];
    while (e != -1) {
        int2 t = next_src[e];
        float sd = s_dst[t.y * NH + hd];
        float a0 = ss + sd;
        a0 = a0 > 0.f ? a0 : 0.2f * a0;
        sum += __expf(a0);
        e = t.x;
    }
    sum += __shfl_xor(sum, 4, 64);
    sum += __shfl_xor(sum, 8, 64);
    sum += __shfl_xor(sum, 16, 64);
    sum += __shfl_xor(sum, 32, 64);
    if (lane < 4) ssi[n * NH + lane].y = 1.f / (sum + 1e-10f);
}

// ---------------------------------------------------------------- gather
// one wave per dst node; each 32-lane half walks 4 of the node's 8 chains
// (8 dependency streams/wave). Lane covers 8 channels (shortx8 = 16B h-load).
// Loads phased: {4x next} -> {4x ssi,h} -> {FMAs} so the chases overlap.
// Halves combined by cross-half shfl; single coalesced store. NO atomics.
__global__ __launch_bounds__(256) void gather_kernel(const int* __restrict__ head_dst,
                              const int2* __restrict__ next_dst,
                              const float2* __restrict__ ssi,
                              const float* __restrict__ s_dst,
                              const ushort* __restrict__ h,
                              const float* __restrict__ bias,
                              float* __restrict__ out, int M) {
    int lane = threadIdx.x & 63;
    int n = blockIdx.x * 4 + (threadIdx.x >> 6);
    if (n >= M) return;
    int half = lane >> 5;
    int l5 = lane & 31;
    int head = l5 >> 3;            // 8 lanes per head
    int c0 = l5 * 8;               // channel base 0..248
    float sdst = s_dst[n * NH + head];
    floatx4 accA = {0.f, 0.f, 0.f, 0.f}, accB = {0.f, 0.f, 0.f, 0.f};
    int e0 = head_dst[8 * n + 4 * half + 0];
    int e1 = head_dst[8 * n + 4 * half + 1];
    int e2 = head_dst[8 * n + 4 * half + 2];
    int e3 = head_dst[8 * n + 4 * half + 3];

    while (e0 != -1 || e1 != -1 || e2 != -1 || e3 != -1) {
        bool b0 = e0 != -1, b1 = e1 != -1, b2 = e2 != -1, b3 = e3 != -1;
        int2 t0, t1, t2, t3;
        // phase 1: all chain-next loads in flight
        if (b0) t0 = next_dst[e0];
        if (b1) t1 = next_dst[e1];
        if (b2) t2 = next_dst[e2];
        if (b3) t3 = next_dst[e3];
        // phase 2: all payload loads in flight
        float2 si0, si1, si2, si3;
        shortx8 h0, h1, h2, h3;
        if (b0) { si0 = ssi[(size_t)t0.y * NH + head]; h0 = *(const shortx8*)&h[(size_t)t0.y * HD + c0]; }
        if (b1) { si1 = ssi[(size_t)t1.y * NH + head]; h1 = *(const shortx8*)&h[(size_t)t1.y * HD + c0]; }
        if (b2) { si2 = ssi[(size_t)t2.y * NH + head]; h2 = *(const shortx8*)&h[(size_t)t2.y * HD + c0]; }
        if (b3) { si3 = ssi[(size_t)t3.y * NH + head]; h3 = *(const shortx8*)&h[(size_t)t3.y * HD + c0]; }
        // phase 3: compute
#define GAT_EDGE(B, SI, HU, EV, TV) do {                                       \
        if (B) {                                                               \
            float es_ = (SI).x + sdst;                                         \
            es_ = es_ > 0.f ? es_ : 0.2f * es_;                                \
            float al_ = __expf(es_) * (SI).y;                                  \
            accA.x += al_ * bf2f((ushort)(HU)[0]);                             \
            accA.y += al_ * bf2f((ushort)(HU)[1]);                             \
            accA.z += al_ * bf2f((ushort)(HU)[2]);                             \
            accA.w += al_ * bf2f((ushort)(HU)[3]);                             \
            accB.x += al_ * bf2f((ushort)(HU)[4]);                             \
            accB.y += al_ * bf2f((ushort)(HU)[5]);                             \
            accB.z += al_ * bf2f((ushort)(HU)[6]);                             \
            accB.w += al_ * bf2f((ushort)(HU)[7]);                             \
            EV = (TV).x;                                                       \
        }                                                                      \
    } while (0)
        GAT_EDGE(b0, si0, h0, e0, t0);
        GAT_EDGE(b1, si1, h1, e1, t1);
        GAT_EDGE(b2, si2, h2, e2, t2);
        GAT_EDGE(b3, si3, h3, e3, t3);
#undef GAT_EDGE
    }

    // combine the two halves (same channels, different edges)
    accA.x += __shfl_xor(accA.x, 32, 64); accA.y += __shfl_xor(accA.y, 32, 64);
    accA.z += __shfl_xor(accA.z, 32, 64); accA.w += __shfl_xor(accA.w, 32, 64);
    accB.x += __shfl_xor(accB.x, 32, 64); accB.y += __shfl_xor(accB.y, 32, 64);
    accB.z += __shfl_xor(accB.z, 32, 64); accB.w += __shfl_xor(accB.w, 32, 64);
    if (half == 0) {
        float4 b0 = *(const float4*)&bias[c0];
        float4 b1 = *(const float4*)&bias[c0 + 4];
        float4 o0 = make_float4(accA.x + b0.x, accA.y + b0.y, accA.z + b0.z, accA.w + b0.w);
        float4 o1 = make_float4(accB.x + b1.x, accB.y + b1.y, accB.z + b1.z, accB.w + b1.w);
        *(float4*)&out[(size_t)n * HD + c0] = o0;
        *(float4*)&out[(size_t)n * HD + c0 + 4] = o1;
    }
}

// ---------------------------------------------------------------- launch
extern "C" void kernel_launch(void* const* d_in, const int* in_sizes, int n_in,
                              void* d_out, int out_size, void* d_ws, size_t ws_size,
                              hipStream_t stream) {
    const float* x     = (const float*)d_in[0];
    const int2*  edges = (const int2*)d_in[1];
    const float* W     = (const float*)d_in[2];
    const float* a     = (const float*)d_in[3];
    const float* bias  = (const float*)d_in[4];
    float* out = (float*)d_out;
    const int M = in_sizes[0] / IN_DIM;   // 50000
    const int E = in_sizes[1] / 2;        // 800000

    char* p = (char*)d_ws;
    ushort* hB       = (ushort*)p; p += (size_t)M * HD * sizeof(ushort);     // 25.6 MB
    ushort* Wt       = (ushort*)p; p += (size_t)HD * IN_DIM * sizeof(ushort);
    float*  s_dst    = (float*)p;  p += (size_t)M * NH * sizeof(float);
    float2* ssi      = (float2*)p; p += (size_t)M * NH * sizeof(float2);     // {s_src, inv_sum}
    int*    head_src = (int*)p;    p += (size_t)16 * M * sizeof(int);        // 3.2 MB
    int*    head_dst = (int*)p;    p += (size_t)8 * M * sizeof(int);         // 1.6 MB
    int2*   next_src = (int2*)p;   p += (size_t)E * sizeof(int2);            // 6.4 MB
    int2*   next_dst = (int2*)p;   p += (size_t)E * sizeof(int2);            // 6.4 MB

    prep_kernel<<<(16 * M + 255) / 256, 256, 0, stream>>>(W, Wt, head_src, head_dst, M);
    gemm_kernel<<<(M + 63) / 64, 256, 0, stream>>>(x, Wt, hB, a, ssi, s_dst, M);
    link_kernel<<<(E + 255) / 256, 256, 0, stream>>>(edges, head_src, next_src,
                                                     head_dst, next_dst, E);
    src_sum_kernel<<<(M + 3) / 4, 256, 0, stream>>>(head_src, next_src, ssi, s_dst, M);
    gather_kernel<<<(M + 3) / 4, 256, 0, stream>>>(head_dst, next_dst, ssi, s_dst,
                                                   hB, bias, out, M);
}